// Round 4
// baseline (192.587 us; speedup 1.0000x reference)
//
#include <hip/hip_runtime.h>

typedef short bf16x8 __attribute__((ext_vector_type(8)));
typedef float f32x4 __attribute__((ext_vector_type(4)));

#define MFMA16(a, b, c) __builtin_amdgcn_mfma_f32_16x16x32_bf16(a, b, c, 0, 0, 0)

__device__ inline short f2bf(float f) {  // RNE, scalar epilogue use
  unsigned u = __builtin_bit_cast(unsigned, f);
  u += 0x7FFFu + ((u >> 16) & 1u);
  return (short)(u >> 16);
}
// pack two fp32 -> 2 bf16 in one dword; round-half-up (+0x8000) then v_perm byte-pack.
__device__ inline unsigned pack2(float lo, float hi) {
  unsigned a = __builtin_bit_cast(unsigned, lo) + 0x8000u;
  unsigned b = __builtin_bit_cast(unsigned, hi) + 0x8000u;
  return __builtin_amdgcn_perm(b, a, 0x07060302u);
}

// LDS row stride 68 shorts (=34 dwords): B-transpose b32 writes spread over 16 banks
// (2-way = free, m136); A b128 writes/reads and MFMA fragment reads stay at the
// wave64 8-dword/bank minimum. (Old stride 72 gave 4-way on B writes: 3.5M conflicts.)
#define LDST 68

// ---------------------------------------------------------------------------
// ws layout (bytes):
//   qs  = 0       : 256x1024 bf16 (524288)   Qs (pre-scaled by 1/32)
//   kwb = 524288  : 320x1024 bf16 (655360)   rows 0..209=K, 210..274=wk, 275..287=0
//   vt  = 1179648 : 1024x256 bf16 (524288)   V transposed [n][m]
//   Abf = 1703936 : 256x256  bf16 (131072)   A padded (cols>=210 zeroed)
//   av  = 1835008 : 256x1024 bf16 (524288)   A@V
// ---------------------------------------------------------------------------

// QKV: C[210x3072] = [Xmaj@Wq*scale | Xmin@Wk | Xmin@Wv], bf16 out, fp32 inputs.
// BK=128 (16 phases), depth-2 register prefetch: loads for tile t+1 stay in flight
// across the barriers while tile t is packed+MFMA'd (fine-grained vmcnt on reg loads).
__global__ __launch_bounds__(256, 1) void k_qkv(const float* __restrict__ xmaj,
                                                const float* __restrict__ xmin,
                                                const float* __restrict__ Wq,
                                                const float* __restrict__ Wk,
                                                const float* __restrict__ Wv,
                                                const float* __restrict__ wkin,
                                                short* __restrict__ qs,
                                                short* __restrict__ kwb,
                                                short* __restrict__ vt) {
  int b = blockIdx.x;
  int t = threadIdx.x;
  if (b >= 192) {  // tail: convert wk (65x1024) into kwb rows 210..274, zero 275..287
    int idx = (b - 192) * 256 + t;
    const float4* src = (const float4*)wkin;
    uint2* dst = (uint2*)(kwb + 210 * 1024);
    for (int i = idx; i < 16640; i += 512) {
      float4 v = src[i];
      dst[i] = make_uint2(pack2(v.x, v.y), pack2(v.z, v.w));
    }
    uint4 z = make_uint4(0, 0, 0, 0);
    uint4* zd = (uint4*)(kwb + 275 * 1024);
    for (int i = idx; i < 1664; i += 512) zd[i] = z;
    return;
  }

  __shared__ short As[2][64 * LDST];  // [k-chunk][row*LDST+col]
  __shared__ short Bs[2][64 * LDST];
  int x = b & 7, s = b >> 3;
  int ntile = x * 6 + (s >> 2);
  int mtile = s & 3;
  int nn0 = ntile * 64;
  int mat = nn0 >> 10;
  int ncol0 = nn0 & 1023;
  int m0 = mtile * 64;
  const float* Xa = (mat == 0) ? xmaj : xmin;
  const float* W = (mat == 0) ? Wq : (mat == 1 ? Wk : Wv);
  int lane = t & 63, w = t >> 6;
  int wm = w >> 1, wn = w & 1;
  int l15 = lane & 15, l4 = lane >> 4;
  f32x4 acc[2][2] = {};
  int arow = t >> 3, ac8 = t & 7;
  int bkp = t >> 4, bc4 = t & 15;
  int g1 = m0 + arow; if (g1 > 209) g1 = 209;
  int g2 = m0 + arow + 32; if (g2 > 209) g2 = 209;
  const float* xr1 = Xa + (size_t)g1 * 2048 + ac8 * 8;
  const float* xr2 = Xa + (size_t)g2 * 2048 + ac8 * 8;
  const float* wb = W + ncol0 + bc4 * 4;

  float4 ra0[8], rb0[8], ra1[8], rb1[8];

  auto load = [&](int kt, float4* ra, float4* rb) {
#pragma unroll
    for (int c = 0; c < 2; ++c) {
      int kc = kt + 64 * c;
      ra[c * 4 + 0] = *(const float4*)(xr1 + kc);
      ra[c * 4 + 1] = *(const float4*)(xr1 + kc + 4);
      ra[c * 4 + 2] = *(const float4*)(xr2 + kc);
      ra[c * 4 + 3] = *(const float4*)(xr2 + kc + 4);
#pragma unroll
      for (int h = 0; h < 2; ++h) {
        const float* gp = wb + (size_t)(kc + 2 * (bkp + 16 * h)) * 1024;
        rb[c * 4 + 2 * h + 0] = *(const float4*)gp;
        rb[c * 4 + 2 * h + 1] = *(const float4*)(gp + 1024);
      }
    }
  };
  auto pack = [&](const float4* ra, const float4* rb) {
#pragma unroll
    for (int c = 0; c < 2; ++c) {
      const float4 &a0 = ra[c * 4 + 0], &a1 = ra[c * 4 + 1];
      *(uint4*)&As[c][arow * LDST + ac8 * 8] =
          make_uint4(pack2(a0.x, a0.y), pack2(a0.z, a0.w), pack2(a1.x, a1.y), pack2(a1.z, a1.w));
      const float4 &a2 = ra[c * 4 + 2], &a3 = ra[c * 4 + 3];
      *(uint4*)&As[c][(arow + 32) * LDST + ac8 * 8] =
          make_uint4(pack2(a2.x, a2.y), pack2(a2.z, a2.w), pack2(a3.x, a3.y), pack2(a3.z, a3.w));
#pragma unroll
      for (int h = 0; h < 2; ++h) {
        int kp2 = 2 * (bkp + 16 * h);
        const float4 &u = rb[c * 4 + 2 * h], &v = rb[c * 4 + 2 * h + 1];
        *(unsigned*)&Bs[c][(bc4 * 4 + 0) * LDST + kp2] = pack2(u.x, v.x);
        *(unsigned*)&Bs[c][(bc4 * 4 + 1) * LDST + kp2] = pack2(u.y, v.y);
        *(unsigned*)&Bs[c][(bc4 * 4 + 2) * LDST + kp2] = pack2(u.z, v.z);
        *(unsigned*)&Bs[c][(bc4 * 4 + 3) * LDST + kp2] = pack2(u.w, v.w);
      }
    }
  };
  auto mfma_all = [&]() {
#pragma unroll
    for (int c = 0; c < 2; ++c)
#pragma unroll
      for (int kk = 0; kk < 2; ++kk) {
        int ko = kk * 32 + l4 * 8;
        bf16x8 a0 = *(const bf16x8*)&As[c][(wm * 32 + l15) * LDST + ko];
        bf16x8 a1 = *(const bf16x8*)&As[c][(wm * 32 + 16 + l15) * LDST + ko];
        bf16x8 b0 = *(const bf16x8*)&Bs[c][(wn * 32 + l15) * LDST + ko];
        bf16x8 b1 = *(const bf16x8*)&Bs[c][(wn * 32 + 16 + l15) * LDST + ko];
        acc[0][0] = MFMA16(a0, b0, acc[0][0]);
        acc[0][1] = MFMA16(a0, b1, acc[0][1]);
        acc[1][0] = MFMA16(a1, b0, acc[1][0]);
        acc[1][1] = MFMA16(a1, b1, acc[1][1]);
      }
  };

  load(0, ra0, rb0);
#pragma unroll 1
  for (int it = 0; it < 16; it += 2) {
    load((it + 1) * 128, ra1, rb1);
    __syncthreads();
    pack(ra0, rb0);
    __syncthreads();
    mfma_all();
    if (it + 2 < 16) load((it + 2) * 128, ra0, rb0);
    __syncthreads();
    pack(ra1, rb1);
    __syncthreads();
    mfma_all();
  }

  if (mat < 2) {
    float scale = (mat == 0) ? 0.03125f : 1.0f;
    short* dst = (mat == 0) ? qs : kwb;
#pragma unroll
    for (int mi = 0; mi < 2; ++mi)
#pragma unroll
      for (int ni = 0; ni < 2; ++ni) {
        int r0 = m0 + wm * 32 + mi * 16 + l4 * 4;
        int c = ncol0 + wn * 32 + ni * 16 + l15;
        for (int j = 0; j < 4; ++j) {
          int r = r0 + j;
          if (r < 210) dst[r * 1024 + c] = f2bf(acc[mi][ni][j] * scale);
        }
      }
  } else {
    // V: transpose tile via LDS (As[0] reused), store Vt[n][m] coalesced
    __syncthreads();
#pragma unroll
    for (int mi = 0; mi < 2; ++mi)
#pragma unroll
      for (int ni = 0; ni < 2; ++ni) {
        int nl = wn * 32 + ni * 16 + l15;
        int ml0 = wm * 32 + mi * 16 + l4 * 4;
        for (int j = 0; j < 4; ++j) As[0][nl * LDST + ml0 + j] = f2bf(acc[mi][ni][j]);
      }
    __syncthreads();
    for (int h = 0; h < 2; ++h) {
      int idx = t + h * 256;
      int nl = idx >> 3, c8 = idx & 7;
      int mg0 = m0 + c8 * 8;
      short* dstp = vt + (ncol0 + nl) * 256 + mg0;
      if (mg0 + 8 <= 210) {
        *(uint4*)dstp = *(const uint4*)&As[0][nl * LDST + c8 * 8];
      } else {
        for (int e = 0; e < 8; ++e)
          if (mg0 + e < 210) dstp[e] = As[0][nl * LDST + c8 * 8 + e];
      }
    }
  }
}

// Fused S' + softmax. 7 blocks x 32 rows. BK=128 (8 phases), depth-2 reg prefetch.
#define SST 292
__global__ __launch_bounds__(256, 1) void k_attn(const short* __restrict__ qs,
                                                 const short* __restrict__ kwb,
                                                 const int* __restrict__ table,
                                                 short* __restrict__ Abf,
                                                 float* __restrict__ outA) {
  __shared__ short As[2][32 * LDST];
  __shared__ short Bs[2][320 * LDST];  // 87040 B; aliased by Ssh after K-loop
  float* Ssh = (float*)&Bs[0][0];      // 32 x SST floats = 37376 B
  int m0 = blockIdx.x * 32;
  int t = threadIdx.x, lane = t & 63, w = t >> 6;
  int l15 = lane & 15, l4 = lane >> 4;
  f32x4 acc[2][5] = {};
  int arow = t >> 3, ac8 = t & 7;
  const short* qrow = qs + (m0 + arow) * 1024 + ac8 * 8;

  uint4 rA0[2], rA1[2], rB0[20], rB1[20];
  auto load = [&](int kt, uint4* rA, uint4* rB) {
#pragma unroll
    for (int c = 0; c < 2; ++c) {
      int kc = kt + 64 * c;
      rA[c] = *(const uint4*)(qrow + kc);
#pragma unroll
      for (int j = 0; j < 10; ++j) {
        int sj = t + j * 256;
        rB[c * 10 + j] = *(const uint4*)(kwb + (sj >> 3) * 1024 + kc + (sj & 7) * 8);
      }
    }
  };
  auto pack = [&](const uint4* rA, const uint4* rB) {
#pragma unroll
    for (int c = 0; c < 2; ++c) {
      *(uint4*)&As[c][arow * LDST + ac8 * 8] = rA[c];
#pragma unroll
      for (int j = 0; j < 10; ++j) {
        int sj = t + j * 256;
        *(uint4*)&Bs[c][(sj >> 3) * LDST + (sj & 7) * 8] = rB[c * 10 + j];
      }
    }
  };
  auto mfma_all = [&]() {
#pragma unroll
    for (int c = 0; c < 2; ++c)
#pragma unroll
      for (int kk = 0; kk < 2; ++kk) {
        int ko = kk * 32 + l4 * 8;
        bf16x8 a0 = *(const bf16x8*)&As[c][l15 * LDST + ko];
        bf16x8 a1 = *(const bf16x8*)&As[c][(16 + l15) * LDST + ko];
#pragma unroll
        for (int ni = 0; ni < 5; ++ni) {
          bf16x8 bb = *(const bf16x8*)&Bs[c][(w * 80 + ni * 16 + l15) * LDST + ko];
          acc[0][ni] = MFMA16(a0, bb, acc[0][ni]);
          acc[1][ni] = MFMA16(a1, bb, acc[1][ni]);
        }
      }
  };

  load(0, rA0, rB0);
#pragma unroll 1
  for (int it = 0; it < 8; it += 2) {
    load((it + 1) * 128, rA1, rB1);
    __syncthreads();
    pack(rA0, rB0);
    __syncthreads();
    mfma_all();
    if (it + 2 < 8) load((it + 2) * 128, rA0, rB0);
    __syncthreads();
    pack(rA1, rB1);
    __syncthreads();
    mfma_all();
  }

  __syncthreads();  // all Bs reads done before aliasing as Ssh
#pragma unroll
  for (int mi = 0; mi < 2; ++mi)
#pragma unroll
    for (int ni = 0; ni < 5; ++ni) {
      int col = w * 80 + ni * 16 + l15;
      if (col < 288) {
        int r0 = mi * 16 + l4 * 4;
        for (int jj = 0; jj < 4; ++jj) Ssh[(r0 + jj) * SST + col] = acc[mi][ni][jj];
      }
    }
  __syncthreads();

  int r = t >> 3, c = t & 7;
  int row = m0 + r;
  float* Sr = Ssh + r * SST;
  if (row < 210) {
    const int* tr = table + row * 210;
    float mx = -1e30f;
    for (int j = c; j < 210; j += 8) {
      float lg = Sr[j] + Sr[210 + tr[j]];
      Sr[j] = lg;
      mx = fmaxf(mx, lg);
    }
    for (int o = 4; o; o >>= 1) mx = fmaxf(mx, __shfl_xor(mx, o, 8));
    float sum = 0.0f;
    for (int j = c; j < 210; j += 8) {
      float e = __expf(Sr[j] - mx);
      Sr[j] = e;
      sum += e;
    }
    for (int o = 4; o; o >>= 1) sum += __shfl_xor(sum, o, 8);
    float inv = 1.0f / sum;
    for (int j = c; j < 210; j += 8) {
      float a = Sr[j] * inv;
      outA[row * 210 + j] = a;
      Abf[row * 256 + j] = f2bf(a);
    }
    for (int j = 210 + c; j < 256; j += 8) Abf[row * 256 + j] = 0;
  } else {
    for (int j = c; j < 256; j += 8) Abf[row * 256 + j] = 0;
  }
}

// AV = A(pad bf16) @ V via Vt[n][k]. 64x64 tiles, grid(16,4), K=256 = 2 phases of BK=128.
__global__ __launch_bounds__(256, 1) void k_av(const short* __restrict__ Abf,
                                               const short* __restrict__ vt,
                                               short* __restrict__ av) {
  __shared__ short As[2][64 * LDST];
  __shared__ short Bs[2][64 * LDST];
  int n0 = blockIdx.x * 64, m0 = blockIdx.y * 64;
  int t = threadIdx.x, lane = t & 63, w = t >> 6;
  int wm = w >> 1, wn = w & 1;
  int l15 = lane & 15, l4 = lane >> 4;
  f32x4 acc[2][2] = {};
  int arow = t >> 3, ac8 = t & 7;
  const short* ap1 = Abf + (m0 + arow) * 256 + ac8 * 8;
  const short* ap2 = ap1 + 32 * 256;
  const short* bp1 = vt + (n0 + arow) * 256 + ac8 * 8;
  const short* bp2 = bp1 + 32 * 256;

  uint4 rA0[4], rA1[4], rB0[4], rB1[4];
  auto load = [&](int kt, uint4* rA, uint4* rB) {
#pragma unroll
    for (int c = 0; c < 2; ++c) {
      int kc = kt + 64 * c;
      rA[c * 2 + 0] = *(const uint4*)(ap1 + kc);
      rA[c * 2 + 1] = *(const uint4*)(ap2 + kc);
      rB[c * 2 + 0] = *(const uint4*)(bp1 + kc);
      rB[c * 2 + 1] = *(const uint4*)(bp2 + kc);
    }
  };
  auto pack = [&](const uint4* rA, const uint4* rB) {
#pragma unroll
    for (int c = 0; c < 2; ++c) {
      *(uint4*)&As[c][arow * LDST + ac8 * 8] = rA[c * 2 + 0];
      *(uint4*)&As[c][(arow + 32) * LDST + ac8 * 8] = rA[c * 2 + 1];
      *(uint4*)&Bs[c][arow * LDST + ac8 * 8] = rB[c * 2 + 0];
      *(uint4*)&Bs[c][(arow + 32) * LDST + ac8 * 8] = rB[c * 2 + 1];
    }
  };
  auto mfma_all = [&]() {
#pragma unroll
    for (int c = 0; c < 2; ++c)
#pragma unroll
      for (int kk = 0; kk < 2; ++kk) {
        int ko = kk * 32 + l4 * 8;
        bf16x8 a0 = *(const bf16x8*)&As[c][(wm * 32 + l15) * LDST + ko];
        bf16x8 a1 = *(const bf16x8*)&As[c][(wm * 32 + 16 + l15) * LDST + ko];
        bf16x8 b0 = *(const bf16x8*)&Bs[c][(wn * 32 + l15) * LDST + ko];
        bf16x8 b1 = *(const bf16x8*)&Bs[c][(wn * 32 + 16 + l15) * LDST + ko];
        acc[0][0] = MFMA16(a0, b0, acc[0][0]);
        acc[0][1] = MFMA16(a0, b1, acc[0][1]);
        acc[1][0] = MFMA16(a1, b0, acc[1][0]);
        acc[1][1] = MFMA16(a1, b1, acc[1][1]);
      }
  };

  load(0, rA0, rB0);
  load(128, rA1, rB1);
  __syncthreads();
  pack(rA0, rB0);
  __syncthreads();
  mfma_all();
  __syncthreads();
  pack(rA1, rB1);
  __syncthreads();
  mfma_all();

#pragma unroll
  for (int mi = 0; mi < 2; ++mi)
#pragma unroll
    for (int ni = 0; ni < 2; ++ni) {
      int r0 = m0 + wm * 32 + mi * 16 + l4 * 4;
      int c = n0 + wn * 32 + ni * 16 + l15;
      for (int j = 0; j < 4; ++j) {
        int r = r0 + j;
        if (r < 210) av[r * 1024 + c] = f2bf(acc[mi][ni][j]);
      }
    }
}

// Y = AV @ Wo : BK=128 (8 phases), depth-2 reg prefetch, Wo transpose-packed in staging. fp32 out.
__global__ __launch_bounds__(256, 1) void k_y(const short* __restrict__ av,
                                              const float* __restrict__ Wo,
                                              float* __restrict__ outY) {
  __shared__ short As[2][64 * LDST];
  __shared__ short Bs[2][64 * LDST];
  int n0 = blockIdx.x * 64, m0 = blockIdx.y * 64;
  int t = threadIdx.x, lane = t & 63, w = t >> 6;
  int wm = w >> 1, wn = w & 1;
  int l15 = lane & 15, l4 = lane >> 4;
  f32x4 acc[2][2] = {};
  int arow = t >> 3, ac8 = t & 7;
  int bkp = t >> 4, bc4 = t & 15;
  const short* ar1 = av + (m0 + arow) * 1024 + ac8 * 8;
  const short* ar2 = ar1 + 32 * 1024;
  const float* wb = Wo + n0 + bc4 * 4;

  uint4 ra0[4], ra1[4];
  float4 rb0[8], rb1[8];
  auto load = [&](int kt, uint4* ra, float4* rb) {
#pragma unroll
    for (int c = 0; c < 2; ++c) {
      int kc = kt + 64 * c;
      ra[c * 2 + 0] = *(const uint4*)(ar1 + kc);
      ra[c * 2 + 1] = *(const uint4*)(ar2 + kc);
#pragma unroll
      for (int h = 0; h < 2; ++h) {
        const float* gp = wb + (size_t)(kc + 2 * (bkp + 16 * h)) * 1024;
        rb[c * 4 + 2 * h + 0] = *(const float4*)gp;
        rb[c * 4 + 2 * h + 1] = *(const float4*)(gp + 1024);
      }
    }
  };
  auto pack = [&](const uint4* ra, const float4* rb) {
#pragma unroll
    for (int c = 0; c < 2; ++c) {
      *(uint4*)&As[c][arow * LDST + ac8 * 8] = ra[c * 2 + 0];
      *(uint4*)&As[c][(arow + 32) * LDST + ac8 * 8] = ra[c * 2 + 1];
#pragma unroll
      for (int h = 0; h < 2; ++h) {
        int kp2 = 2 * (bkp + 16 * h);
        const float4 &u = rb[c * 4 + 2 * h], &v = rb[c * 4 + 2 * h + 1];
        *(unsigned*)&Bs[c][(bc4 * 4 + 0) * LDST + kp2] = pack2(u.x, v.x);
        *(unsigned*)&Bs[c][(bc4 * 4 + 1) * LDST + kp2] = pack2(u.y, v.y);
        *(unsigned*)&Bs[c][(bc4 * 4 + 2) * LDST + kp2] = pack2(u.z, v.z);
        *(unsigned*)&Bs[c][(bc4 * 4 + 3) * LDST + kp2] = pack2(u.w, v.w);
      }
    }
  };
  auto mfma_all = [&]() {
#pragma unroll
    for (int c = 0; c < 2; ++c)
#pragma unroll
      for (int kk = 0; kk < 2; ++kk) {
        int ko = kk * 32 + l4 * 8;
        bf16x8 a0 = *(const bf16x8*)&As[c][(wm * 32 + l15) * LDST + ko];
        bf16x8 a1 = *(const bf16x8*)&As[c][(wm * 32 + 16 + l15) * LDST + ko];
        bf16x8 b0 = *(const bf16x8*)&Bs[c][(wn * 32 + l15) * LDST + ko];
        bf16x8 b1 = *(const bf16x8*)&Bs[c][(wn * 32 + 16 + l15) * LDST + ko];
        acc[0][0] = MFMA16(a0, b0, acc[0][0]);
        acc[0][1] = MFMA16(a0, b1, acc[0][1]);
        acc[1][0] = MFMA16(a1, b0, acc[1][0]);
        acc[1][1] = MFMA16(a1, b1, acc[1][1]);
      }
  };

  load(0, ra0, rb0);
#pragma unroll 1
  for (int it = 0; it < 8; it += 2) {
    load((it + 1) * 128, ra1, rb1);
    __syncthreads();
    pack(ra0, rb0);
    __syncthreads();
    mfma_all();
    if (it + 2 < 8) load((it + 2) * 128, ra0, rb0);
    __syncthreads();
    pack(ra1, rb1);
    __syncthreads();
    mfma_all();
  }

#pragma unroll
  for (int mi = 0; mi < 2; ++mi)
#pragma unroll
    for (int ni = 0; ni < 2; ++ni) {
      int r0 = m0 + wm * 32 + mi * 16 + l4 * 4;
      int c = n0 + wn * 32 + ni * 16 + l15;
      for (int j = 0; j < 4; ++j) {
        int r = r0 + j;
        if (r < 210) outY[r * 1024 + c] = acc[mi][ni][j];
      }
    }
}

extern "C" void kernel_launch(void* const* d_in, const int* in_sizes, int n_in,
                              void* d_out, int out_size, void* d_ws, size_t ws_size,
                              hipStream_t stream) {
  const float* Xmaj = (const float*)d_in[0];
  const float* Xmin = (const float*)d_in[1];
  const float* Wq = (const float*)d_in[2];
  const float* Wk = (const float*)d_in[3];
  const float* Wv = (const float*)d_in[4];
  const float* Wo = (const float*)d_in[5];
  const float* wk = (const float*)d_in[6];
  const int* table = (const int*)d_in[7];

  char* ws = (char*)d_ws;
  short* qs = (short*)(ws + 0);
  short* kwb = (short*)(ws + 524288);
  short* vt = (short*)(ws + 1179648);
  short* Abf = (short*)(ws + 1703936);
  short* av = (short*)(ws + 1835008);

  float* outY = (float*)d_out;           // 210*1024 fp32
  float* outA = (float*)d_out + 215040;  // 210*210 fp32

  k_qkv<<<194, 256, 0, stream>>>(Xmaj, Xmin, Wq, Wk, Wv, wk, qs, kwb, vt);
  k_attn<<<7, 256, 0, stream>>>(qs, kwb, table, Abf, outA);
  k_av<<<dim3(16, 4), 256, 0, stream>>>(Abf, vt, av);
  k_y<<<dim3(16, 4), 256, 0, stream>>>(av, Wo, outY);
}

// Round 5
// 127.000 us; speedup vs baseline: 1.5164x; 1.5164x over previous
//
#include <hip/hip_runtime.h>

typedef short bf16x8 __attribute__((ext_vector_type(8)));
typedef float f32x4 __attribute__((ext_vector_type(4)));

#define MFMA16(a, b, c) __builtin_amdgcn_mfma_f32_16x16x32_bf16(a, b, c, 0, 0, 0)

__device__ inline short f2bf(float f) {  // RNE, epilogue use
  unsigned u = __builtin_bit_cast(unsigned, f);
  u += 0x7FFFu + ((u >> 16) & 1u);
  return (short)(u >> 16);
}
// pack two fp32 -> 2 bf16 in one dword; round-half-up then v_perm byte-pack.
__device__ inline unsigned pack2(float lo, float hi) {
  unsigned a = __builtin_bit_cast(unsigned, lo) + 0x8000u;
  unsigned b = __builtin_bit_cast(unsigned, hi) + 0x8000u;
  return __builtin_amdgcn_perm(b, a, 0x07060302u);
}

// Async 16B global->LDS (zero VGPR round-trip). lds ptr must be the wave-uniform
// lane-0 base; HW writes lane i at base + 16*i (m104/m108).
__device__ inline void async_cp16(const void* g, void* l) {
  __builtin_amdgcn_global_load_lds(
      (const __attribute__((address_space(1))) unsigned int*)g,
      (__attribute__((address_space(3))) unsigned int*)l, 16, 0, 0);
}

// Swizzled LDS tile, NCH=16 chunks (8 shorts) per row, unpadded (global_load_lds
// requires contiguity). Slot (r,c) holds global chunk c^(r&7): staging is lane-linear
// (conflict-free), frag ds_read_b128 spreads 8 lanes per 4-bank group (minimum).
#define SWZ(r, c) ((((r) << 4) + ((c) ^ ((r) & 7))) << 3)

// ---------------------------------------------------------------------------
// ws layout (bytes):
//   xmaj_bf  0        : 256x2048 bf16 (1048576)  rows>=210 poison (finite, unused)
//   xmin_bf  1048576  : 256x2048 bf16 (1048576)
//   qs       2097152  : 256x1024 bf16 (524288)   Qs (pre-scaled by 1/32)
//   kwb      2621440  : 320x1024 bf16 (655360)   0..209=K, 210..274=wk, 275..287=0
//   vt       3276800  : 1024x256 bf16 (524288)   V transposed [n][m]
//   Abf      3801088  : 256x256  bf16 (131072)   A padded, zeros outside 210x210
//   av       3932160  : 256x1024 bf16 (524288)   A@V (rows<210 valid)
//   Sp       4456448  : 224x320  f32  (286720)   S' = Qs @ [K;wk]^T
//   wqt      4743168  : 1024x2048 bf16 (4194304) Wq^T
//   wkt      8937472  : 1024x2048 bf16 (4194304) Wk^T
//   wvt      13131776 : 1024x2048 bf16 (4194304) Wv^T
//   wot      17326080 : 1024x1024 bf16 (2097152) Wo^T
// ---------------------------------------------------------------------------

// Prep: blocks [0,512) convert X_major/X_minor/wk to bf16 (+ zero kwb rows 275..287);
// blocks [512,2048) transpose+convert Wq/Wk/Wv (64x64 tiles); [2048,2304) Wo.
__global__ __launch_bounds__(256) void k_prep(const float* __restrict__ xmaj,
                                              const float* __restrict__ xmin,
                                              const float* __restrict__ wkin,
                                              const float* __restrict__ Wq,
                                              const float* __restrict__ Wk,
                                              const float* __restrict__ Wv,
                                              const float* __restrict__ Wo,
                                              short* __restrict__ xmaj_bf,
                                              short* __restrict__ xmin_bf,
                                              short* __restrict__ kwb,
                                              short* __restrict__ wqt,
                                              short* __restrict__ wkt,
                                              short* __restrict__ wvt,
                                              short* __restrict__ wot) {
  __shared__ short tile[64][72];  // stride 72 shorts = 144 B: 16B-aligned rows
  int b = blockIdx.x, t = threadIdx.x;
  if (b < 512) {
    int idx = b * 256 + t;
    if (idx < 107520) {  // 210*2048/4
      float4 v = ((const float4*)xmaj)[idx];
      ((uint2*)xmaj_bf)[idx] = make_uint2(pack2(v.x, v.y), pack2(v.z, v.w));
      float4 u = ((const float4*)xmin)[idx];
      ((uint2*)xmin_bf)[idx] = make_uint2(pack2(u.x, u.y), pack2(u.z, u.w));
    }
    if (idx < 16640) {  // 65*1024/4
      float4 v = ((const float4*)wkin)[idx];
      ((uint2*)(kwb + 210 * 1024))[idx] = make_uint2(pack2(v.x, v.y), pack2(v.z, v.w));
    }
    if (idx < 1664) ((uint4*)(kwb + 275 * 1024))[idx] = make_uint4(0, 0, 0, 0);
    return;
  }
  const float* W;
  short* Wt;
  int kt, nt, dstK;
  if (b < 2048) {
    int wi = (b - 512) >> 9, tl = (b - 512) & 511;
    W = wi == 0 ? Wq : (wi == 1 ? Wk : Wv);
    Wt = wi == 0 ? wqt : (wi == 1 ? wkt : wvt);
    kt = tl >> 4; nt = tl & 15; dstK = 2048;
  } else {
    int tl = b - 2048;
    W = Wo; Wt = wot; kt = tl >> 4; nt = tl & 15; dstK = 1024;
  }
  int k0 = kt * 64, n0 = nt * 64;
  int kp = t >> 4, nl4 = (t & 15) * 4;
  for (int h = 0; h < 2; ++h) {
    int kpp = kp + h * 16;
    const float* g = W + (size_t)(k0 + 2 * kpp) * 1024 + n0 + nl4;
    float4 u = *(const float4*)g;
    float4 v = *(const float4*)(g + 1024);
    *(unsigned*)&tile[nl4 + 0][2 * kpp] = pack2(u.x, v.x);
    *(unsigned*)&tile[nl4 + 1][2 * kpp] = pack2(u.y, v.y);
    *(unsigned*)&tile[nl4 + 2][2 * kpp] = pack2(u.z, v.z);
    *(unsigned*)&tile[nl4 + 3][2 * kpp] = pack2(u.w, v.w);
  }
  __syncthreads();
  int nl = t >> 2, cq = t & 3;
  for (int h = 0; h < 2; ++h) {
    int c = cq + h * 4;
    *(uint4*)(Wt + (size_t)(n0 + nl) * dstK + k0 + c * 8) = *(const uint4*)&tile[nl][c * 8];
  }
}

// QKV: [Xmaj@Wq*scale | Xmin@Wk | Xmin@Wv], all-bf16 async staging, BK=128, 16 phases.
// 192 blocks, XCD swizzle: 4 m-tiles sharing a weight tile land on one XCD.
__global__ __launch_bounds__(256, 1) void k_qkv(const short* __restrict__ xmaj,
                                                const short* __restrict__ xmin,
                                                const short* __restrict__ wqt,
                                                const short* __restrict__ wkt,
                                                const short* __restrict__ wvt,
                                                short* __restrict__ qs,
                                                short* __restrict__ kwb,
                                                short* __restrict__ vt) {
  __shared__ short As[64 * 128];
  __shared__ short Bs[64 * 128];
  int b = blockIdx.x, t = threadIdx.x;
  int x = b & 7, s = b >> 3;
  int ntile = x * 6 + (s >> 2), mtile = s & 3;
  int nn0 = ntile * 64;
  int mat = nn0 >> 10, ncol0 = nn0 & 1023, m0 = mtile * 64;
  const short* A = (mat == 0) ? xmaj : xmin;
  const short* Bt = (mat == 0) ? wqt : (mat == 1 ? wkt : wvt);
  int lane = t & 63, w = t >> 6;
  int wm = w >> 1, wn = w & 1;
  int l15 = lane & 15, l4 = lane >> 4;
  f32x4 acc[2][2] = {};

  for (int k0 = 0; k0 < 2048; k0 += 128) {
    __syncthreads();
#pragma unroll
    for (int j = 0; j < 4; ++j) {
      int sj = t + j * 256;
      int r = sj >> 4, cg = (sj & 15) ^ (r & 7);
      async_cp16(A + (size_t)(m0 + r) * 2048 + k0 + cg * 8, &As[(w * 64 + j * 256) * 8]);
    }
#pragma unroll
    for (int j = 0; j < 4; ++j) {
      int sj = t + j * 256;
      int r = sj >> 4, cg = (sj & 15) ^ (r & 7);
      async_cp16(Bt + (size_t)(ncol0 + r) * 2048 + k0 + cg * 8, &Bs[(w * 64 + j * 256) * 8]);
    }
    __syncthreads();
#pragma unroll
    for (int kk = 0; kk < 4; ++kk) {
      int c = kk * 4 + l4;
      int ra0 = wm * 32 + l15, ra1 = ra0 + 16;
      int rb0 = wn * 32 + l15, rb1 = rb0 + 16;
      bf16x8 a0 = *(const bf16x8*)&As[SWZ(ra0, c)];
      bf16x8 a1 = *(const bf16x8*)&As[SWZ(ra1, c)];
      bf16x8 b0 = *(const bf16x8*)&Bs[SWZ(rb0, c)];
      bf16x8 b1 = *(const bf16x8*)&Bs[SWZ(rb1, c)];
      acc[0][0] = MFMA16(a0, b0, acc[0][0]);
      acc[0][1] = MFMA16(a0, b1, acc[0][1]);
      acc[1][0] = MFMA16(a1, b0, acc[1][0]);
      acc[1][1] = MFMA16(a1, b1, acc[1][1]);
    }
  }

  if (mat < 2) {
    float scale = (mat == 0) ? 0.03125f : 1.0f;
    short* dst = (mat == 0) ? qs : kwb;
#pragma unroll
    for (int mi = 0; mi < 2; ++mi)
#pragma unroll
      for (int ni = 0; ni < 2; ++ni) {
        int r0 = m0 + wm * 32 + mi * 16 + l4 * 4;
        int c = ncol0 + wn * 32 + ni * 16 + l15;
        for (int j = 0; j < 4; ++j) {
          int r = r0 + j;
          if (r < 210) dst[r * 1024 + c] = f2bf(acc[mi][ni][j] * scale);
        }
      }
  } else {
    // V: transpose via LDS (reuse As, stride 72 for aligned uint4 reads), store Vt[n][m]
    __syncthreads();
#pragma unroll
    for (int mi = 0; mi < 2; ++mi)
#pragma unroll
      for (int ni = 0; ni < 2; ++ni) {
        int nl = wn * 32 + ni * 16 + l15;
        int ml0 = wm * 32 + mi * 16 + l4 * 4;
        for (int j = 0; j < 4; ++j) As[nl * 72 + ml0 + j] = f2bf(acc[mi][ni][j]);
      }
    __syncthreads();
    for (int h = 0; h < 2; ++h) {
      int idx = t + h * 256;
      int nl = idx >> 3, c8 = idx & 7;
      int mg0 = m0 + c8 * 8;
      short* dstp = vt + (ncol0 + nl) * 256 + mg0;
      if (mg0 + 8 <= 210) {
        *(uint4*)dstp = *(const uint4*)&As[nl * 72 + c8 * 8];
      } else {
        for (int e = 0; e < 8; ++e)
          if (mg0 + e < 210) dstp[e] = As[nl * 72 + c8 * 8 + e];
      }
    }
  }
}

// S' = Qs @ [K;wk]^T -> Sp[224][320] fp32. Tiles 32x64, grid (5,7), K=1024, 8 phases.
__global__ __launch_bounds__(256, 1) void k_sprime(const short* __restrict__ qs,
                                                   const short* __restrict__ kwb,
                                                   float* __restrict__ Sp) {
  __shared__ short As[32 * 128];
  __shared__ short Bs[64 * 128];
  int n0 = blockIdx.x * 64, m0 = blockIdx.y * 32;
  int t = threadIdx.x, lane = t & 63, w = t >> 6;
  int l15 = lane & 15, l4 = lane >> 4;
  f32x4 acc[2] = {};

  for (int k0 = 0; k0 < 1024; k0 += 128) {
    __syncthreads();
#pragma unroll
    for (int j = 0; j < 2; ++j) {
      int sj = t + j * 256;
      int r = sj >> 4, cg = (sj & 15) ^ (r & 7);
      async_cp16(qs + (size_t)(m0 + r) * 1024 + k0 + cg * 8, &As[(w * 64 + j * 256) * 8]);
    }
#pragma unroll
    for (int j = 0; j < 4; ++j) {
      int sj = t + j * 256;
      int r = sj >> 4, cg = (sj & 15) ^ (r & 7);
      async_cp16(kwb + (size_t)(n0 + r) * 1024 + k0 + cg * 8, &Bs[(w * 64 + j * 256) * 8]);
    }
    __syncthreads();
#pragma unroll
    for (int kk = 0; kk < 4; ++kk) {
      int c = kk * 4 + l4;
      int rb = w * 16 + l15;
      bf16x8 a0 = *(const bf16x8*)&As[SWZ(l15, c)];
      bf16x8 a1 = *(const bf16x8*)&As[SWZ(16 + l15, c)];
      bf16x8 bb = *(const bf16x8*)&Bs[SWZ(rb, c)];
      acc[0] = MFMA16(a0, bb, acc[0]);
      acc[1] = MFMA16(a1, bb, acc[1]);
    }
  }
#pragma unroll
  for (int mi = 0; mi < 2; ++mi) {
    int r0 = m0 + mi * 16 + l4 * 4;
    int col = n0 + w * 16 + l15;
    for (int j = 0; j < 4; ++j) Sp[(r0 + j) * 320 + col] = acc[mi][j];
  }
}

// softmax rows: logits[i][j] = Sp[i][j] + Sp[i][210+table[i][j]]; writes fp32 A (d_out)
// and bf16 Abf (padded 256x256, zeros outside).
__global__ __launch_bounds__(256) void k_softmax(const float* __restrict__ Sp,
                                                 const int* __restrict__ table,
                                                 short* __restrict__ Abf,
                                                 float* __restrict__ outA) {
  int i = blockIdx.x, t = threadIdx.x;
  if (i >= 210) {
    Abf[i * 256 + t] = 0;
    return;
  }
  __shared__ float srow[288];
  __shared__ float red[4];
  for (int j = t; j < 288; j += 256) srow[j] = Sp[i * 320 + j];
  __syncthreads();
  float logit = -1e30f;
  if (t < 210) {
    int tb = table[i * 210 + t];
    logit = srow[t] + srow[210 + tb];
  }
  float m = logit;
  for (int o = 32; o; o >>= 1) m = fmaxf(m, __shfl_xor(m, o));
  if ((t & 63) == 0) red[t >> 6] = m;
  __syncthreads();
  m = fmaxf(fmaxf(red[0], red[1]), fmaxf(red[2], red[3]));
  float e = (t < 210) ? __expf(logit - m) : 0.0f;
  float s = e;
  for (int o = 32; o; o >>= 1) s += __shfl_xor(s, o);
  __syncthreads();
  if ((t & 63) == 0) red[t >> 6] = s;
  __syncthreads();
  s = red[0] + red[1] + red[2] + red[3];
  float a = e / s;
  Abf[i * 256 + t] = (t < 210) ? f2bf(a) : (short)0;
  if (t < 210) outA[i * 210 + t] = a;
}

// AV = A(pad bf16) @ V via Vt[n][k]. 64x64 tiles, grid(16,4), K=256, 2 phases.
__global__ __launch_bounds__(256, 1) void k_av(const short* __restrict__ Abf,
                                               const short* __restrict__ vt,
                                               short* __restrict__ av) {
  __shared__ short As[64 * 128];
  __shared__ short Bs[64 * 128];
  int n0 = blockIdx.x * 64, m0 = blockIdx.y * 64;
  int t = threadIdx.x, lane = t & 63, w = t >> 6;
  int wm = w >> 1, wn = w & 1;
  int l15 = lane & 15, l4 = lane >> 4;
  f32x4 acc[2][2] = {};

  for (int k0 = 0; k0 < 256; k0 += 128) {
    __syncthreads();
#pragma unroll
    for (int j = 0; j < 4; ++j) {
      int sj = t + j * 256;
      int r = sj >> 4, cg = (sj & 15) ^ (r & 7);
      async_cp16(Abf + (size_t)(m0 + r) * 256 + k0 + cg * 8, &As[(w * 64 + j * 256) * 8]);
      async_cp16(vt + (size_t)(n0 + r) * 256 + k0 + cg * 8, &Bs[(w * 64 + j * 256) * 8]);
    }
    __syncthreads();
#pragma unroll
    for (int kk = 0; kk < 4; ++kk) {
      int c = kk * 4 + l4;
      int ra0 = wm * 32 + l15, ra1 = ra0 + 16;
      int rb0 = wn * 32 + l15, rb1 = rb0 + 16;
      bf16x8 a0 = *(const bf16x8*)&As[SWZ(ra0, c)];
      bf16x8 a1 = *(const bf16x8*)&As[SWZ(ra1, c)];
      bf16x8 b0 = *(const bf16x8*)&Bs[SWZ(rb0, c)];
      bf16x8 b1 = *(const bf16x8*)&Bs[SWZ(rb1, c)];
      acc[0][0] = MFMA16(a0, b0, acc[0][0]);
      acc[0][1] = MFMA16(a0, b1, acc[0][1]);
      acc[1][0] = MFMA16(a1, b0, acc[1][0]);
      acc[1][1] = MFMA16(a1, b1, acc[1][1]);
    }
  }
#pragma unroll
  for (int mi = 0; mi < 2; ++mi)
#pragma unroll
    for (int ni = 0; ni < 2; ++ni) {
      int r0 = m0 + wm * 32 + mi * 16 + l4 * 4;
      int c = n0 + wn * 32 + ni * 16 + l15;
      for (int j = 0; j < 4; ++j) {
        int r = r0 + j;
        if (r < 210) av[r * 1024 + c] = f2bf(acc[mi][ni][j]);
      }
    }
}

// Y = AV @ Wo via wot[n][k]. 64x64 tiles, grid(16,4), K=1024, 8 phases. fp32 out.
__global__ __launch_bounds__(256, 1) void k_y(const short* __restrict__ av,
                                              const short* __restrict__ wot,
                                              float* __restrict__ outY) {
  __shared__ short As[64 * 128];
  __shared__ short Bs[64 * 128];
  int n0 = blockIdx.x * 64, m0 = blockIdx.y * 64;
  int t = threadIdx.x, lane = t & 63, w = t >> 6;
  int wm = w >> 1, wn = w & 1;
  int l15 = lane & 15, l4 = lane >> 4;
  f32x4 acc[2][2] = {};

  for (int k0 = 0; k0 < 1024; k0 += 128) {
    __syncthreads();
#pragma unroll
    for (int j = 0; j < 4; ++j) {
      int sj = t + j * 256;
      int r = sj >> 4, cg = (sj & 15) ^ (r & 7);
      async_cp16(av + (size_t)(m0 + r) * 1024 + k0 + cg * 8, &As[(w * 64 + j * 256) * 8]);
      async_cp16(wot + (size_t)(n0 + r) * 1024 + k0 + cg * 8, &Bs[(w * 64 + j * 256) * 8]);
    }
    __syncthreads();
#pragma unroll
    for (int kk = 0; kk < 4; ++kk) {
      int c = kk * 4 + l4;
      int ra0 = wm * 32 + l15, ra1 = ra0 + 16;
      int rb0 = wn * 32 + l15, rb1 = rb0 + 16;
      bf16x8 a0 = *(const bf16x8*)&As[SWZ(ra0, c)];
      bf16x8 a1 = *(const bf16x8*)&As[SWZ(ra1, c)];
      bf16x8 b0 = *(const bf16x8*)&Bs[SWZ(rb0, c)];
      bf16x8 b1 = *(const bf16x8*)&Bs[SWZ(rb1, c)];
      acc[0][0] = MFMA16(a0, b0, acc[0][0]);
      acc[0][1] = MFMA16(a0, b1, acc[0][1]);
      acc[1][0] = MFMA16(a1, b0, acc[1][0]);
      acc[1][1] = MFMA16(a1, b1, acc[1][1]);
    }
  }
#pragma unroll
  for (int mi = 0; mi < 2; ++mi)
#pragma unroll
    for (int ni = 0; ni < 2; ++ni) {
      int r0 = m0 + wm * 32 + mi * 16 + l4 * 4;
      int c = n0 + wn * 32 + ni * 16 + l15;
      for (int j = 0; j < 4; ++j) {
        int r = r0 + j;
        if (r < 210) outY[r * 1024 + c] = acc[mi][ni][j];
      }
    }
}

extern "C" void kernel_launch(void* const* d_in, const int* in_sizes, int n_in,
                              void* d_out, int out_size, void* d_ws, size_t ws_size,
                              hipStream_t stream) {
  const float* Xmaj = (const float*)d_in[0];
  const float* Xmin = (const float*)d_in[1];
  const float* Wq = (const float*)d_in[2];
  const float* Wk = (const float*)d_in[3];
  const float* Wv = (const float*)d_in[4];
  const float* Wo = (const float*)d_in[5];
  const float* wk = (const float*)d_in[6];
  const int* table = (const int*)d_in[7];

  char* ws = (char*)d_ws;
  short* xmaj_bf = (short*)(ws + 0);
  short* xmin_bf = (short*)(ws + 1048576);
  short* qs = (short*)(ws + 2097152);
  short* kwb = (short*)(ws + 2621440);
  short* vt = (short*)(ws + 3276800);
  short* Abf = (short*)(ws + 3801088);
  short* av = (short*)(ws + 3932160);
  float* Sp = (float*)(ws + 4456448);
  short* wqt = (short*)(ws + 4743168);
  short* wkt = (short*)(ws + 8937472);
  short* wvt = (short*)(ws + 13131776);
  short* wot = (short*)(ws + 17326080);

  float* outY = (float*)d_out;           // 210*1024 fp32
  float* outA = (float*)d_out + 215040;  // 210*210 fp32

  k_prep<<<2304, 256, 0, stream>>>(Xmaj, Xmin, wk, Wq, Wk, Wv, Wo,
                                   xmaj_bf, xmin_bf, kwb, wqt, wkt, wvt, wot);
  k_qkv<<<192, 256, 0, stream>>>(xmaj_bf, xmin_bf, wqt, wkt, wvt, qs, kwb, vt);
  k_sprime<<<dim3(5, 7), 256, 0, stream>>>(qs, kwb, Sp);
  k_softmax<<<256, 256, 0, stream>>>(Sp, table, Abf, outA);
  k_av<<<dim3(16, 4), 256, 0, stream>>>(Abf, vt, av);
  k_y<<<dim3(16, 4), 256, 0, stream>>>(av, wot, outY);
}